// Round 1
// baseline (151.171 us; speedup 1.0000x reference)
//
#include <hip/hip_runtime.h>
#include <math.h>

namespace {

constexpr int BB  = 4;    // batch
constexpr int SS  = 512;  // detector bins == image size
constexpr int AA  = 180;  // angles
constexpr int PAD = 112;  // LDS row zero-pad each side: p in [-105.9, 616.9]
constexpr int ROWBUF = SS + 2 * PAD;  // 736 floats

// ---------------------------------------------------------------------------
// Kernel 1: ramp filter as direct Toeplitz convolution.
//   xf[b][a][n] = 0.5*x[b,n,a] + sum_{m: parity(m)!=parity(n)} h[n-m]*x[b,m,a]
//   h[d] = -2/(pi*d)^2 for odd d (h is zero at even d != 0).
//   Compact table hh[k] = h[2k-511], k in [0,512)  (2k-511 is always odd).
// Output stored transposed: [B][A][S] so backprojection staging is contiguous.
// ---------------------------------------------------------------------------
__global__ __launch_bounds__(256) void ramp_filter_kernel(
    const float* __restrict__ x, float* __restrict__ xf) {
  __shared__ float xs[SS];
  __shared__ float hh[SS];
  const int t   = threadIdx.x;
  const int blk = blockIdx.x;        // b*AA + a
  const int b   = blk / AA;
  const int a   = blk - b * AA;

  // stage column x[b, :, a] (global stride AA floats)
  const float* xcol = x + (size_t)b * (SS * AA) + a;
  xs[t]       = xcol[(size_t)t * AA];
  xs[t + 256] = xcol[(size_t)(t + 256) * AA];

  // build compact odd-tap table
  {
    const double c = -2.0 / (M_PI * M_PI);
    double d0 = (double)(2 * t - 511);
    double d1 = (double)(2 * (t + 256) - 511);
    hh[t]       = (float)(c / (d0 * d0));
    hh[t + 256] = (float)(c / (d1 * d1));
  }
  __syncthreads();

  // thread t computes outputs n0 = t and n1 = t+256 (same parity)
  const int pt = t & 1;
  float acc0 = 0.5f * xs[t];
  float acc1 = 0.5f * xs[t + 256];
  int m = 1 - pt;                 // opposite-parity m: pt=0 -> m odd; pt=1 -> m even
  int k = (t - m + 511) >> 1;     // exact integer; k1 = k + 128
#pragma unroll 8
  for (int j = 0; j < 256; ++j) {
    float xv = xs[m];
    float h0 = hh[k];
    float h1 = hh[k + 128];       // -> ds_read2_b32
    acc0 = fmaf(xv, h0, acc0);
    acc1 = fmaf(xv, h1, acc1);
    m += 2;
    --k;
  }
  float* orow = xf + (size_t)blk * SS;  // [b][a][*]
  orow[t]       = acc0;
  orow[t + 256] = acc1;
}

// ---------------------------------------------------------------------------
// Kernel 2: backprojection.
// Block = one batch x (64-wide x 16-tall) pixel tile; 256 threads, 4 pixels
// per thread (same x, 4 y-rows). Per angle: stage detector row into
// zero-padded LDS, then p = x*ca - y*sa + K; lerp via ds_read2_b32.
// Zero pads implement grid_sample zeros-padding with no clamps/flags.
// ---------------------------------------------------------------------------
__global__ __launch_bounds__(256) void backproject_kernel(
    const float* __restrict__ xf, float* __restrict__ out) {
  __shared__ float  row[ROWBUF];
  __shared__ float2 trig[AA];

  const int t  = threadIdx.x;
  const int tx = blockIdx.x;  // 0..7   x-tile (64 px)
  const int ty = blockIdx.y;  // 0..31  y-tile (16 px)
  const int b  = blockIdx.z;

  // zero the pads (once; first __syncthreads in the loop publishes them)
  if (t < PAD) { row[t] = 0.0f; row[PAD + SS + t] = 0.0f; }
  // trig table, scale folded: p_buf = x*(c*255.5) - y*(s*255.5) + (255.5+PAD)
  if (t < AA) {
    float th = (float)t * (float)(M_PI / 180.0);
    float s, c;
    sincosf(th, &s, &c);
    trig[t] = make_float2(c * 255.5f, s * 255.5f);
  }

  const int lx = t & 63;
  const int r  = t >> 6;  // 0..3
  const int gx = tx * 64 + lx;
  // EXACT replication of jnp.linspace(-1,1,512) + f32 mask math (no FMA!)
  const float step = 2.0f / 511.0f;
  const float xg = __fadd_rn(-1.0f, __fmul_rn((float)gx, step));
  float yg[4];
  int   gy[4];
#pragma unroll
  for (int kk = 0; kk < 4; ++kk) {
    gy[kk] = ty * 16 + r + 4 * kk;
    yg[kk] = __fadd_rn(-1.0f, __fmul_rn((float)gy[kk], step));
  }

  float acc[4] = {0.f, 0.f, 0.f, 0.f};
  const float* src = xf + (size_t)b * (AA * SS);
  const float  K   = 255.5f + (float)PAD;

  for (int a = 0; a < AA; ++a) {
    // stage row [a]: 256 threads x float2 = 512 floats, coalesced
    float2 v = ((const float2*)(src + a * SS))[t];
    ((float2*)(row + PAD))[t] = v;   // PAD=112 floats -> 448B, 8B-aligned
    __syncthreads();

    float2 cs  = trig[a];
    float base = fmaf(xg, cs.x, K);
#pragma unroll
    for (int kk = 0; kk < 4; ++kk) {
      float p  = fmaf(-yg[kk], cs.y, base);  // p in [6.1, 728.9] > 0
      float fp = floorf(p);
      int   i0 = (int)fp;
      float w  = p - fp;
      float v0 = row[i0];
      float v1 = row[i0 + 1];                // -> ds_read2_b32
      acc[kk] = fmaf(w, v1 - v0, acc[kk] + v0);
    }
    __syncthreads();
  }

  // epilogue: circle mask (bit-exact f32 replication) + pi/(2A) scale
  const float scale = (float)(M_PI / (2.0 * AA));
  const float xx = __fmul_rn(xg, xg);
#pragma unroll
  for (int kk = 0; kk < 4; ++kk) {
    float ss  = __fadd_rn(xx, __fmul_rn(yg[kk], yg[kk]));
    float val = (ss <= 1.0f) ? acc[kk] * scale : 0.0f;
    out[((size_t)b * SS + gy[kk]) * SS + gx] = val;
  }
}

}  // namespace

extern "C" void kernel_launch(void* const* d_in, const int* in_sizes, int n_in,
                              void* d_out, int out_size, void* d_ws, size_t ws_size,
                              hipStream_t stream) {
  const float* x  = (const float*)d_in[0];
  float*       out = (float*)d_out;
  float*       xf  = (float*)d_ws;  // [B][A][S] = 4*180*512 floats = 1.44 MB

  ramp_filter_kernel<<<BB * AA, 256, 0, stream>>>(x, xf);
  backproject_kernel<<<dim3(SS / 64, SS / 16, BB), 256, 0, stream>>>(xf, out);
}

// Round 2
// 118.559 us; speedup vs baseline: 1.2751x; 1.2751x over previous
//
#include <hip/hip_runtime.h>
#include <math.h>

namespace {

constexpr int BB  = 4;    // batch
constexpr int SS  = 512;  // detector bins == image size
constexpr int AA  = 180;  // angles
constexpr int PAD = 112;  // LDS row zero-pad each side: p in [6.1, 728.9]
constexpr int ROWBUF = SS + 2 * PAD;  // 736 floats
constexpr int ANG = 4;                // angles staged per barrier
constexpr int NG  = AA / ANG;         // 45 groups

// ---------------------------------------------------------------------------
// Kernel 1: ramp filter as direct Toeplitz convolution.
//   xf[b][a][n] = 0.5*x[b,n,a] + sum_{m: parity(m)!=parity(n)} h[n-m]*x[b,m,a]
//   h[d] = -2/(pi*d)^2 for odd d; zero for even d != 0; h[0]=0.5 handled apart.
//   hh[k] = h[2k-511], k in [0,512).
// Grid: (BB*AA, 2): each block computes 256 of the 512 outputs (1/thread)
// -> 1440 blocks = 5.6 blocks/CU for latency hiding (prev 720 was 2.8/CU and
// each thread ran a 256-iter LDS chain with addr arithmetic -> ~55 us).
// Output transposed: [B][A][S].
// ---------------------------------------------------------------------------
__global__ __launch_bounds__(256) void ramp_filter_kernel(
    const float* __restrict__ x, float* __restrict__ xf) {
  __shared__ float xs[SS];
  __shared__ float hh[SS];
  const int t    = threadIdx.x;
  const int blk  = blockIdx.x;        // b*AA + a
  const int half = blockIdx.y;        // 0/1: which 256 outputs
  const int b    = blk / AA;
  const int a    = blk - b * AA;

  // stage column x[b, :, a] (global stride AA floats; L2-resident after 1st use)
  const float* xcol = x + (size_t)b * (SS * AA) + a;
  xs[t]       = xcol[(size_t)t * AA];
  xs[t + 256] = xcol[(size_t)(t + 256) * AA];

  // f32 tap table (taps ~1e-7 rel vs f64 build -> irrelevant at 4.4e-3 thr)
  {
    const float c = (float)(-2.0 / (M_PI * M_PI));
    float d0 = (float)(2 * t - 511);
    float d1 = (float)(2 * (t + 256) - 511);
    hh[t]       = c / (d0 * d0);
    hh[t + 256] = c / (d1 * d1);
  }
  __syncthreads();

  const int n  = half * 256 + t;
  float acc = 0.5f * xs[n];
  const int m0 = 1 - (n & 1);          // opposite parity start
  const int k0 = (n - m0 + 511) >> 1;  // tap index for m0 (then decrements)
  const float* xp = xs + m0;
  const float* hp = hh + k0;
  // same accumulation order as R1 (m ascending) to keep rounding identical
#pragma unroll 16
  for (int j = 0; j < 256; ++j) {
    acc = fmaf(xp[2 * j], hp[-j], acc);
  }
  xf[(size_t)blk * SS + n] = acc;
}

// ---------------------------------------------------------------------------
// Kernel 2: backprojection, 4 angles per barrier + double-buffered LDS.
// Block = one batch x (64-wide x 16-tall) pixel tile; 256 threads, 4 pixels
// per thread. Per group of 4 angles: prefetch next group's 4 rows from global
// (2 float4/thread), compute 16 lerps on current buffer, write prefetched
// rows to the other buffer, ONE barrier. 45 barriers total (was 360).
// Zero-padded rows implement grid_sample zeros-padding with no clamps.
// ---------------------------------------------------------------------------
__global__ __launch_bounds__(256) void backproject_kernel(
    const float* __restrict__ xf, float* __restrict__ out) {
  __shared__ float  rows[2 * ANG * ROWBUF];  // 2 x 4 x 736 floats = 23 KB
  __shared__ float2 trig[AA];

  const int t  = threadIdx.x;
  const int tx = blockIdx.x;  // 0..7   x-tile (64 px)
  const int ty = blockIdx.y;  // 0..31  y-tile (16 px)
  const int b  = blockIdx.z;

  // zero ONLY the pad regions (data region is raced by stagers otherwise)
  // 8 rows x 2 pads x 112 floats = 1792
  for (int i = t; i < 2 * ANG * 2 * PAD; i += 256) {
    int row = i / (2 * PAD);
    int o   = i - row * (2 * PAD);
    int off = (o < PAD) ? o : (o + SS);
    rows[row * ROWBUF + off] = 0.0f;
  }
  // trig table, scale folded: p = x*(c*255.5) - y*(s*255.5) + (255.5+PAD)
  if (t < AA) {
    float th = (float)t * (float)(M_PI / 180.0);
    float s, c;
    sincosf(th, &s, &c);
    trig[t] = make_float2(c * 255.5f, s * 255.5f);
  }

  const int lx = t & 63;
  const int r  = t >> 6;  // 0..3
  const int gx = tx * 64 + lx;
  // EXACT replication of jnp.linspace(-1,1,512) + f32 mask math (no FMA!)
  const float step = 2.0f / 511.0f;
  const float xg = __fadd_rn(-1.0f, __fmul_rn((float)gx, step));
  float yg[4];
  int   gy[4];
#pragma unroll
  for (int kk = 0; kk < 4; ++kk) {
    gy[kk] = ty * 16 + r + 4 * kk;
    yg[kk] = __fadd_rn(-1.0f, __fmul_rn((float)gy[kk], step));
  }

  const float4* src4 = (const float4*)(xf + (size_t)b * (AA * SS));
  const float   K    = 255.5f + (float)PAD;

  // prologue: stage group 0 into buffer 0
  {
    float4 q0 = src4[t];
    float4 q1 = src4[t + 256];
    int f0 = t, f1 = t + 256;
    ((float4*)&rows[(f0 >> 7) * ROWBUF + PAD])[f0 & 127] = q0;
    ((float4*)&rows[(f1 >> 7) * ROWBUF + PAD])[f1 & 127] = q1;
  }
  __syncthreads();

  float acc[4] = {0.f, 0.f, 0.f, 0.f};
  int buf = 0;

  for (int g = 0; g < NG; ++g) {
    // prefetch next group's rows (overlaps with compute below)
    float4 n0, n1;
    const bool more = (g + 1 < NG);
    if (more) {
      n0 = src4[(g + 1) * 512 + t];
      n1 = src4[(g + 1) * 512 + t + 256];
    }

    const float* bufp = rows + buf * (ANG * ROWBUF);
#pragma unroll
    for (int aa = 0; aa < ANG; ++aa) {
      float2 cs   = trig[g * ANG + aa];
      float  base = fmaf(xg, cs.x, K);
      const float* R = bufp + aa * ROWBUF;
#pragma unroll
      for (int kk = 0; kk < 4; ++kk) {
        float p  = fmaf(-yg[kk], cs.y, base);  // p in [6.1, 728.9] > 0
        int   i0 = (int)p;                     // trunc == floor (p > 0)
        float w  = p - (float)i0;
        float v0 = R[i0];
        float v1 = R[i0 + 1];                  // -> ds_read2_b32
        acc[kk] = fmaf(w, v1 - v0, acc[kk] + v0);
      }
    }

    if (more) {
      float* nbuf = rows + (buf ^ 1) * (ANG * ROWBUF);
      int f0 = t, f1 = t + 256;
      ((float4*)&nbuf[(f0 >> 7) * ROWBUF + PAD])[f0 & 127] = n0;
      ((float4*)&nbuf[(f1 >> 7) * ROWBUF + PAD])[f1 & 127] = n1;
    }
    __syncthreads();
    buf ^= 1;
  }

  // epilogue: circle mask (bit-exact f32 replication) + pi/(2A) scale
  const float scale = (float)(M_PI / (2.0 * AA));
  const float xx = __fmul_rn(xg, xg);
#pragma unroll
  for (int kk = 0; kk < 4; ++kk) {
    float ss  = __fadd_rn(xx, __fmul_rn(yg[kk], yg[kk]));
    float val = (ss <= 1.0f) ? acc[kk] * scale : 0.0f;
    out[((size_t)b * SS + gy[kk]) * SS + gx] = val;
  }
}

}  // namespace

extern "C" void kernel_launch(void* const* d_in, const int* in_sizes, int n_in,
                              void* d_out, int out_size, void* d_ws, size_t ws_size,
                              hipStream_t stream) {
  const float* x   = (const float*)d_in[0];
  float*       out = (float*)d_out;
  float*       xf  = (float*)d_ws;  // [B][A][S] = 4*180*512 floats = 1.44 MB

  ramp_filter_kernel<<<dim3(BB * AA, 2), 256, 0, stream>>>(x, xf);
  backproject_kernel<<<dim3(SS / 64, SS / 16, BB), 256, 0, stream>>>(xf, out);
}